// Round 9
// baseline (323.843 us; speedup 1.0000x reference)
//
#include <hip/hip_runtime.h>

// 2-layer GCN via bucketed counting-sort aggregation with LDS accumulators.
// Round-9 changes vs round-8 (k_l1 is gather-LATENCY bound, not BW bound):
//  - Explicit MLP batching in k_l1 (4 independent gathers in flight) and
//    k_l2 (8) before the LDS atomics.
//  - Sort key refined to (dstBucket, srcQuarter): per-phase gather slice is
//    2 MB (xd) / 1 MB (h2), L2-resident per XCD -> gathers become ~200cy L2
//    hits instead of ~900cy HBM misses.

typedef unsigned int u32;

#define BSHIFT 11            // 2048 nodes per bucket
#define BNODES 2048
#define MAXBINS 2048         // 4*NB must fit; supports N <= 2^20
#define EPB 16384            // edges per block in binning kernels

__device__ __forceinline__ u32 pack_bf16(float a, float b) {  // RTN
    u32 ua = __float_as_uint(a), ub = __float_as_uint(b);
    ua += 0x7FFFu + ((ua >> 16) & 1u);
    ub += 0x7FFFu + ((ub >> 16) & 1u);
    return (ua >> 16) | (ub & 0xFFFF0000u);
}
__device__ __forceinline__ float bf_lo(u32 p) { return __uint_as_float(p << 16); }
__device__ __forceinline__ float bf_hi(u32 p) { return __uint_as_float(p & 0xFFFF0000u); }

__device__ __forceinline__ u32 src_quarter(u32 sv, u32 Q1, u32 Q2, u32 Q3) {
    return (sv >= Q2) ? ((sv >= Q3) ? 3u : 2u) : ((sv >= Q1) ? 1u : 0u);
}

// ---- A1: count edges per (bucket, srcQuarter) bin; save per-block counts ----
__global__ void k_bincount(const int* __restrict__ src, const int* __restrict__ dst,
                           int E, int NBINS, u32 Q1, u32 Q2, u32 Q3,
                           u32* __restrict__ binTotal, u32* __restrict__ bh) {
    __shared__ u32 h[MAXBINS];
    const int tid = threadIdx.x;
    for (int j = tid; j < MAXBINS; j += 256) h[j] = 0;
    __syncthreads();
    const int start = blockIdx.x * EPB;
    const int end = min(start + EPB, E);
    for (int e = start + tid; e < end; e += 256) {
        u32 d = (u32)dst[e];
        u32 b = ((d >> BSHIFT) << 2) | src_quarter((u32)src[e], Q1, Q2, Q3);
        atomicAdd(&h[b], 1u);
    }
    __syncthreads();
    u32* bhrow = bh + (size_t)blockIdx.x * MAXBINS;
    for (int j = tid; j < NBINS; j += 256) {
        u32 c = h[j];
        bhrow[j] = c;
        if (c) atomicAdd(&binTotal[j], c);
    }
}

// ---- A2: exclusive scan of bin totals (1024 threads, 2 bins/thread) ----
__global__ void k_binscan(const u32* __restrict__ binTotal,
                          u32* __restrict__ binBase,
                          u32* __restrict__ cursor, int NBINS, int E) {
    __shared__ u32 s[1024];
    const int tid = threadIdx.x;  // 1024
    const int i0 = 2 * tid, i1 = 2 * tid + 1;
    u32 v0 = (i0 < NBINS) ? binTotal[i0] : 0u;
    u32 v1 = (i1 < NBINS) ? binTotal[i1] : 0u;
    u32 p = v0 + v1;
    s[tid] = p;
    __syncthreads();
    for (int d = 1; d < 1024; d <<= 1) {
        u32 t = (tid >= d) ? s[tid - d] : 0u;
        __syncthreads();
        s[tid] += t;
        __syncthreads();
    }
    u32 excl = s[tid] - p;
    if (i0 < NBINS) { binBase[i0] = excl;      cursor[i0] = excl; }
    if (i1 < NBINS) { binBase[i1] = excl + v0; cursor[i1] = excl + v0; }
    if (tid == 0) binBase[NBINS] = (u32)E;
}

// ---- A3: scatter edges into bin-grouped records ----
// rec = src | (dstLocal << 20)   (src < 2^20, dstLocal < 2^11)
__global__ void k_binscatter(const int* __restrict__ src, const int* __restrict__ dst,
                             int E, int NBINS, u32 Q1, u32 Q2, u32 Q3,
                             u32* __restrict__ cursor,
                             const u32* __restrict__ bh, u32* __restrict__ rec) {
    __shared__ u32 h[MAXBINS];
    const int tid = threadIdx.x;
    const u32* bhrow = bh + (size_t)blockIdx.x * MAXBINS;
    for (int j = tid; j < MAXBINS; j += 256) h[j] = 0;
    __syncthreads();
    for (int j = tid; j < NBINS; j += 256) {
        u32 c = bhrow[j];
        if (c) h[j] = atomicAdd(&cursor[j], c);
    }
    __syncthreads();
    const int start = blockIdx.x * EPB;
    const int end = min(start + EPB, E);
    for (int e = start + tid; e < end; e += 256) {
        u32 d = (u32)dst[e];
        u32 sv = (u32)src[e];
        u32 b = ((d >> BSHIFT) << 2) | src_quarter(sv, Q1, Q2, Q3);
        u32 slot = atomicAdd(&h[b], 1u);
        rec[slot] = sv | ((d & (BNODES - 1u)) << 20);
    }
}

// ---- C: per-bucket degree -> dinv, and xd = x*dinv packed bf16x4 ----
__global__ void k_deg(const u32* __restrict__ rec, const u32* __restrict__ binBase,
                      const float4* __restrict__ x,
                      float* __restrict__ dinv, uint2* __restrict__ xd, int N) {
    __shared__ u32 deg[BNODES];
    const int tid = threadIdx.x;  // 512
    const int b = blockIdx.x;
    for (int j = tid; j < BNODES; j += 512) deg[j] = 0;
    __syncthreads();
    const u32 s0 = binBase[4 * b], s1 = binBase[4 * b + 4];
    for (u32 i = s0 + tid; i < s1; i += 512)
        atomicAdd(&deg[rec[i] >> 20], 1u);
    __syncthreads();
    const int nodeBase = b << BSHIFT;
    for (int n = tid; n < BNODES; n += 512) {
        int gn = nodeBase + n;
        if (gn < N) {
            float d = rsqrtf((float)(deg[n] + 1u));
            dinv[gn] = d;
            float4 xi = x[gn];
            xd[gn] = make_uint2(pack_bf16(xi.x * d, xi.y * d),
                                pack_bf16(xi.z * d, xi.w * d));
        }
    }
}

// ---- D: layer-1 aggregate (LDS) + fused W1/relu/W2 -> h2 (bf16x2) ----
__global__ void k_l1(const u32* __restrict__ rec, const u32* __restrict__ binBase,
                     const float* __restrict__ dinv, const uint2* __restrict__ xd,
                     const float* __restrict__ W1, const float* __restrict__ b1,
                     const float* __restrict__ W2,
                     u32* __restrict__ h2, int N) {
    __shared__ float agg[BNODES * 4];
    const int tid = threadIdx.x;  // 1024
    const int b = blockIdx.x;
    for (int j = tid; j < BNODES * 4; j += 1024) agg[j] = 0.f;
    __syncthreads();
    const u32 s0 = binBase[4 * b], s1 = binBase[4 * b + 4];
    const u32 T = 1024;

#define L1_ACC(R, V) do {                                 \
        float* p = &agg[((R) >> 20) * 4];                 \
        atomicAdd(p + 0, bf_lo((V).x));                   \
        atomicAdd(p + 1, bf_hi((V).x));                   \
        atomicAdd(p + 2, bf_lo((V).y));                   \
        atomicAdd(p + 3, bf_hi((V).y));                   \
    } while (0)

    u32 i = s0 + tid;
    // batch of 4: 4 coalesced rec loads, 4 independent gathers in flight
    for (; i + 3 * T < s1; i += 4 * T) {
        u32 r0 = rec[i], r1 = rec[i + T], r2 = rec[i + 2 * T], r3 = rec[i + 3 * T];
        uint2 v0 = xd[r0 & 0xFFFFFu];
        uint2 v1 = xd[r1 & 0xFFFFFu];
        uint2 v2 = xd[r2 & 0xFFFFFu];
        uint2 v3 = xd[r3 & 0xFFFFFu];
        L1_ACC(r0, v0); L1_ACC(r1, v1); L1_ACC(r2, v2); L1_ACC(r3, v3);
    }
    for (; i < s1; i += T) {
        u32 r = rec[i];
        uint2 v = xd[r & 0xFFFFFu];
        L1_ACC(r, v);
    }
#undef L1_ACC
    __syncthreads();

    const int nodeBase = b << BSHIFT;
    for (int n = tid; n < BNODES; n += 1024) {
        int gn = nodeBase + n;
        if (gn >= N) continue;
        float di = dinv[gn];
        uint2 xs = xd[gn];  // self term already scaled by dinv
        float ax = (bf_lo(xs.x) + agg[n * 4 + 0]) * di;
        float ay = (bf_hi(xs.x) + agg[n * 4 + 1]) * di;
        float az = (bf_lo(xs.y) + agg[n * 4 + 2]) * di;
        float aw = (bf_hi(xs.y) + agg[n * 4 + 3]) * di;
        float g0 = 0.f, g1 = 0.f;
#pragma unroll
        for (int k = 0; k < 16; ++k) {
            float h = ax * W1[k] + ay * W1[16 + k] + az * W1[32 + k] + aw * W1[48 + k] + b1[k];
            h = fmaxf(h, 0.f);
            g0 += h * W2[2 * k];
            g1 += h * W2[2 * k + 1];
        }
        h2[gn] = pack_bf16(g0 * di, g1 * di);
    }
}

// ---- E: layer-2 aggregate (LDS) + fused log_softmax ----
__global__ void k_l2(const u32* __restrict__ rec, const u32* __restrict__ binBase,
                     const float* __restrict__ dinv, const u32* __restrict__ h2,
                     const float* __restrict__ b2, float2* __restrict__ out, int N) {
    __shared__ float agg[BNODES * 2];
    const int tid = threadIdx.x;  // 1024
    const int b = blockIdx.x;
    for (int j = tid; j < BNODES * 2; j += 1024) agg[j] = 0.f;
    __syncthreads();
    const u32 s0 = binBase[4 * b], s1 = binBase[4 * b + 4];
    const u32 T = 1024;

#define L2_ACC(R, V) do {                                 \
        float* p = &agg[((R) >> 20) * 2];                 \
        atomicAdd(p + 0, bf_lo(V));                       \
        atomicAdd(p + 1, bf_hi(V));                       \
    } while (0)

    u32 i = s0 + tid;
    // batch of 8 independent gathers
    for (; i + 7 * T < s1; i += 8 * T) {
        u32 r0 = rec[i],         r1 = rec[i + T],     r2 = rec[i + 2 * T], r3 = rec[i + 3 * T];
        u32 r4 = rec[i + 4 * T], r5 = rec[i + 5 * T], r6 = rec[i + 6 * T], r7 = rec[i + 7 * T];
        u32 v0 = h2[r0 & 0xFFFFFu], v1 = h2[r1 & 0xFFFFFu];
        u32 v2 = h2[r2 & 0xFFFFFu], v3 = h2[r3 & 0xFFFFFu];
        u32 v4 = h2[r4 & 0xFFFFFu], v5 = h2[r5 & 0xFFFFFu];
        u32 v6 = h2[r6 & 0xFFFFFu], v7 = h2[r7 & 0xFFFFFu];
        L2_ACC(r0, v0); L2_ACC(r1, v1); L2_ACC(r2, v2); L2_ACC(r3, v3);
        L2_ACC(r4, v4); L2_ACC(r5, v5); L2_ACC(r6, v6); L2_ACC(r7, v7);
    }
    for (; i < s1; i += T) {
        u32 r = rec[i];
        u32 v = h2[r & 0xFFFFFu];
        L2_ACC(r, v);
    }
#undef L2_ACC
    __syncthreads();

    const int nodeBase = b << BSHIFT;
    for (int n = tid; n < BNODES; n += 1024) {
        int gn = nodeBase + n;
        if (gn >= N) continue;
        float di = dinv[gn];
        u32 self = h2[gn];
        float g0 = (bf_lo(self) + agg[n * 2 + 0]) * di + b2[0];
        float g1 = (bf_hi(self) + agg[n * 2 + 1]) * di + b2[1];
        float m = fmaxf(g0, g1);
        float l = m + logf(expf(g0 - m) + expf(g1 - m));
        out[gn] = make_float2(g0 - l, g1 - l);
    }
}

extern "C" void kernel_launch(void* const* d_in, const int* in_sizes, int n_in,
                              void* d_out, int out_size, void* d_ws, size_t ws_size,
                              hipStream_t stream) {
    const float* x  = (const float*)d_in[0];
    const int*   ei = (const int*)d_in[1];   // [2, E] int32: src row then dst row
    const float* W1 = (const float*)d_in[3];
    const float* b1 = (const float*)d_in[4];
    const float* W2 = (const float*)d_in[5];
    const float* b2 = (const float*)d_in[6];

    const int N = in_sizes[0] / 4;
    const int E = in_sizes[1] / 2;
    const int* src = ei;
    const int* dst = ei + E;
    const int NB = (N + BNODES - 1) >> BSHIFT;  // 489 for N=1e6
    const int NBINS = 4 * NB;                   // 1956
    const u32 Q1 = (u32)(N >> 2), Q2 = (u32)(N >> 1), Q3 = (u32)(3 * (N >> 2));
    const int gA = (E + EPB - 1) / EPB;         // 245

    // Workspace (bytes):
    //   rec  [E u32]      @ 0          (16 MB)
    //   dinv [N f32]      @ 4E         (4 MB)
    //   xd   [N uint2]    @ 4E+4N      (8 MB)  x*dinv packed bf16x4
    //   h2   [N u32]      @ 4E+12N     (4 MB)  h2*dinv packed bf16x2
    //   meta @ 4E+16N: binTotal[2048] | binBase[2049] | cursor[2048] |
    //                  bh[gA*2048]   (~2.03 MB)      total ~34.1 MB
    char* w = (char*)d_ws;
    u32*   rec  = (u32*)(w);
    float* dinv = (float*)(w + 4 * (size_t)E);
    uint2* xd   = (uint2*)(w + 4 * (size_t)E + 4 * (size_t)N);
    u32*   h2   = (u32*)(w + 4 * (size_t)E + 12 * (size_t)N);
    u32*   meta = (u32*)(w + 4 * (size_t)E + 16 * (size_t)N);
    u32*   binTotal = meta;
    u32*   binBase  = meta + MAXBINS;
    u32*   cursor   = meta + 2 * MAXBINS + 1;
    u32*   bh       = meta + 3 * MAXBINS + 2;

    hipMemsetAsync(binTotal, 0, sizeof(u32) * (size_t)NBINS, stream);
    k_bincount<<<gA, 256, 0, stream>>>(src, dst, E, NBINS, Q1, Q2, Q3, binTotal, bh);
    k_binscan<<<1, 1024, 0, stream>>>(binTotal, binBase, cursor, NBINS, E);
    k_binscatter<<<gA, 256, 0, stream>>>(src, dst, E, NBINS, Q1, Q2, Q3, cursor, bh, rec);
    k_deg<<<NB, 512, 0, stream>>>(rec, binBase, (const float4*)x, dinv, xd, N);
    k_l1<<<NB, 1024, 0, stream>>>(rec, binBase, dinv, xd, W1, b1, W2, h2, N);
    k_l2<<<NB, 1024, 0, stream>>>(rec, binBase, dinv, h2, b2, (float2*)d_out, N);
}